// Round 5
// baseline (357.899 us; speedup 1.0000x reference)
//
#include <hip/hip_runtime.h>
#include <hip/hip_bf16.h>

typedef unsigned short u16;
typedef __attribute__((ext_vector_type(8))) short b16x8;   // 8 bf16 (MFMA A/B frag)
typedef __attribute__((ext_vector_type(4))) float f32x4;   // MFMA C/D frag

__device__ __forceinline__ u16 f2bf(float f) {
    union { __hip_bfloat16 h; u16 u; } c;
    c.h = __float2bfloat16(f);      // HW v_cvt (pk-fusable), RTNE
    return c.u;
}

// ---------------------------------------------------------------------------
// K0: pack weights to bf16 [n][k], XOR-swizzled 16B chunks (chunk ^= n&7) so
//     K1/K3 can stage/read linearly-swizzled. 16 blocks.
// ---------------------------------------------------------------------------
__global__ __launch_bounds__(256) void k_pack_w(const float* __restrict__ w0,
                                                const float* __restrict__ w1,
                                                const float* __restrict__ w2,
                                                const float* __restrict__ w3,
                                                u16* __restrict__ dstbase) {
    const int b = blockIdx.x;
    const int tensor = b >> 2;
    const float* src = (tensor == 0) ? w0 : (tensor == 1) ? w1
                     : (tensor == 2) ? w2 : w3;
    u16* dst = dstbase + tensor * 16384;
    const int i0 = (b & 3) * 4096;
    for (int j = threadIdx.x; j < 4096; j += 256) {
        int i = i0 + j;
        int k = i >> 7, n = i & 127;          // src is [k][n]
        int kc = k >> 3, kr = k & 7;
        dst[n * 128 + ((kc ^ (n & 7)) << 3) + kr] = f2bf(src[i]);
    }
}

// ---------------------------------------------------------------------------
// K1: LayerNorm + QKV projection. grid (768, 3), 512 thr, 128 tokens/block.
//     W read straight from global (L1/L2-hot) -> LDS = 32 KB, NO barrier on
//     the Q/K path (sA rows are wave-local).
//     Q,K -> head-major [l][h][t][32]; V -> transposed [l][h][dh][t].
//     Q pre-scaled by dh^-0.5 * log2(e)  (K2 uses exp2 directly).
// ---------------------------------------------------------------------------
struct K1Args {
    const float* x[3];
    const float* lng[3];
    const float* lnb[3];
    const float* bias[3];
    u16* outQ; u16* outK; u16* outVt;
};

__global__ __launch_bounds__(512, 4) void k_ln_proj(K1Args a, const u16* __restrict__ wt) {
    __shared__ u16 sA[16384];   // 128 x 128 bf16, chunk-XOR swizzled (32 KB)
    const int tid = threadIdx.x;
    const int tensor = blockIdx.y;
    const int wv = tid >> 6;
    const u16* wsrc = wt + tensor * 16384;   // global, cached

    // LayerNorm: 4 lanes per token, 128 tokens
    const int r = tid >> 2, sub = tid & 3;
    const int token0 = blockIdx.x * 128;
    const int l = token0 / 384;
    const int tloc0 = token0 % 384;          // 0,128,256 (blocks never straddle l)
    const int ti = tloc0 + r;
    const int nn = ti >> 6, w = ti & 63;
    const float* rowp = a.x[tensor] + (size_t)(nn * 16384 + l * 64 + w) * 128 + sub * 32;
    float v[32];
    float s = 0.f, s2 = 0.f;
#pragma unroll
    for (int j = 0; j < 32; j += 4) {
        float4 f = *(const float4*)(rowp + j);
        v[j] = f.x; v[j + 1] = f.y; v[j + 2] = f.z; v[j + 3] = f.w;
        s  += (f.x + f.y) + (f.z + f.w);
        s2 += (f.x * f.x + f.y * f.y) + (f.z * f.z + f.w * f.w);
    }
    s  += __shfl_xor(s, 1);  s  += __shfl_xor(s, 2);
    s2 += __shfl_xor(s2, 1); s2 += __shfl_xor(s2, 2);
    const float mean = s * (1.f / 128.f);
    const float rstd = rsqrtf(s2 * (1.f / 128.f) - mean * mean + 1e-5f);
    const float* gp = a.lng[tensor];
    const float* bbp = a.lnb[tensor];
#pragma unroll
    for (int j = 0; j < 32; j += 8) {
        int k0 = sub * 32 + j;
        b16x8 tv;
#pragma unroll
        for (int q = 0; q < 8; ++q) {
            int k = k0 + q;
            tv[q] = (short)f2bf((v[j + q] - mean) * rstd * gp[k] + bbp[k]);
        }
        *(b16x8*)(sA + r * 128 + (((k0 >> 3) ^ (r & 7)) << 3)) = tv;
    }
    // NO __syncthreads: wave wv's MFMA reads only rows [wv*16,wv*16+16),
    // written by this wave's own threads (tid>>2 in the same range).

    const int lane = tid & 63, lr = lane & 15, lg = lane >> 4;
    f32x4 acc[8];
#pragma unroll
    for (int i = 0; i < 8; ++i) acc[i] = (f32x4){0.f, 0.f, 0.f, 0.f};
    const int rowA = wv * 16 + lr;
#pragma unroll
    for (int kt = 0; kt < 4; ++kt) {
        const int ch = kt * 4 + lg;
        b16x8 af = *(const b16x8*)(sA + rowA * 128 + ((ch ^ (rowA & 7)) << 3));
#pragma unroll
        for (int nt = 0; nt < 8; ++nt) {
            const int nc = nt * 16 + lr;
            b16x8 bf = *(const b16x8*)(wsrc + nc * 128 + ((ch ^ (nc & 7)) << 3));
            acc[nt] = __builtin_amdgcn_mfma_f32_16x16x32_bf16(af, bf, acc[nt], 0, 0, 0);
        }
    }

    const float* biasp = a.bias[tensor];
    if (tensor != 2) {
        // Q/K epilogue: wave-local LDS round-trip, store head-major [l][h][t][32]
        const float scale = (tensor == 0)
            ? 0.17677669529663687f * 1.4426950408889634f  // dh^-0.5 * log2(e)
            : 1.0f;
        u16* outp = (tensor == 0) ? a.outQ : a.outK;
#pragma unroll
        for (int nt = 0; nt < 8; ++nt) {
            const int col = nt * 16 + lr;
            const float bb = biasp[col];
#pragma unroll
            for (int rg = 0; rg < 4; ++rg) {
                const int rowl = wv * 16 + lg * 4 + rg;
                float val = (acc[nt][rg] + bb) * scale;
                sA[rowl * 128 + (((col >> 3) ^ (rowl & 7)) << 3) + (col & 7)] = f2bf(val);
            }
        }
        const int rrow = wv * 16 + (lane >> 2);
#pragma unroll
        for (int c = 0; c < 4; ++c) {
            int colc = (lane & 3) + c * 4;            // 16B chunk index 0..15
            b16x8 val = *(const b16x8*)(sA + rrow * 128 + ((colc ^ (rrow & 7)) << 3));
            int head = colc >> 2, dh0 = (colc & 3) * 8;
            *(b16x8*)(outp + ((size_t)(l * 4 + head) * 384 + tloc0 + rrow) * 32 + dh0) = val;
        }
    } else {
        // V epilogue: transpose via LDS to [l][h][dh][t]
        __syncthreads();     // all waves done reading their sA fragments
#pragma unroll
        for (int nt = 0; nt < 8; ++nt) {
            const int col = nt * 16 + lr;             // feature 0..127
            const float bb = biasp[col];
#pragma unroll
            for (int rg = 0; rg < 4; ++rg) {
                const int trowl = wv * 16 + lg * 4 + rg;   // local t
                float val = acc[nt][rg] + bb;
                sA[col * 128 + (((trowl >> 3) ^ (col & 7)) << 3) + (trowl & 7)] = f2bf(val);
            }
        }
        __syncthreads();
        const int f = tid >> 2;                        // feature 0..127
        const size_t vb = ((size_t)(l * 4 + (f >> 5)) * 32 + (f & 31)) * 384 + tloc0;
#pragma unroll
        for (int c = 0; c < 4; ++c) {
            int tch = (tid & 3) + c * 4;
            b16x8 val = *(const b16x8*)(sA + f * 128 + ((tch ^ (f & 7)) << 3));
            *(b16x8*)(a.outVt + vb + tch * 8) = val;
        }
    }
}

// ---------------------------------------------------------------------------
// K2: per-(window, head) attention, head-major dense layouts, online softmax
//     over 2 K-halves (sacc 48 regs -> ~4 waves/SIMD). exp2-native.
// ---------------------------------------------------------------------------
__global__ __launch_bounds__(256) void k_attn(const u16* __restrict__ qh,
                                              const u16* __restrict__ kh,
                                              const u16* __restrict__ vt,
                                              u16* __restrict__ ah) {
    __shared__ u16 sK[384 * 32];        // [t][dh], chunk sw = c ^ (t&3) ^ ((t>>2)&3)
    __shared__ u16 sP[4][16 * 104];     // per-wave P chunk (96 t), stride 104
    const int tid = threadIdx.x;
    const int l = blockIdx.x, h = blockIdx.y;
    const size_t base = (size_t)(l * 4 + h) * 12288;   // 384*32

    // stage K: dense 24 KB linear read
#pragma unroll
    for (int it = 0; it < 6; ++it) {
        int idx = it * 256 + tid;             // 0..1535, 16B each
        int t = idx >> 2, c = idx & 3;
        b16x8 kv = *(const b16x8*)(kh + base + (size_t)idx * 8);
        int sw = (c ^ (t & 3) ^ ((t >> 2) & 3)) & 3;
        *(b16x8*)(sK + t * 32 + (sw << 3)) = kv;
    }
    __syncthreads();

    const int wv = tid >> 6, lane = tid & 63, lr = lane & 15, lg = lane >> 4;
    u16* myP = sP[wv];

    for (int qt = wv; qt < 24; qt += 4) {
        b16x8 qf = *(const b16x8*)(qh + base + (size_t)(qt * 16 + lr) * 32 + lg * 8);
        float mrun[4] = {-1e30f, -1e30f, -1e30f, -1e30f};
        float srun[4] = {0.f, 0.f, 0.f, 0.f};
        f32x4 pacc[2];
        pacc[0] = (f32x4){0.f, 0.f, 0.f, 0.f};
        pacc[1] = (f32x4){0.f, 0.f, 0.f, 0.f};
#pragma unroll
        for (int half = 0; half < 2; ++half) {
            f32x4 sacc[12];
#pragma unroll
            for (int kt = 0; kt < 12; ++kt) {
                const int t = half * 192 + kt * 16 + lr;
                const int sw = (lg ^ (t & 3) ^ ((t >> 2) & 3)) & 3;
                b16x8 kf = *(const b16x8*)(sK + t * 32 + (sw << 3));
                sacc[kt] = __builtin_amdgcn_mfma_f32_16x16x32_bf16(
                    qf, kf, (f32x4){0.f, 0.f, 0.f, 0.f}, 0, 0, 0);
            }
            // online softmax per row (q = lg*4+rg spread over 16 lr lanes)
#pragma unroll
            for (int rg = 0; rg < 4; ++rg) {
                float m6[6];
#pragma unroll
                for (int i = 0; i < 6; ++i)
                    m6[i] = fmaxf(sacc[2 * i][rg], sacc[2 * i + 1][rg]);
                float tm = fmaxf(fmaxf(fmaxf(m6[0], m6[1]), fmaxf(m6[2], m6[3])),
                                 fmaxf(m6[4], m6[5]));
                tm = fmaxf(tm, __shfl_xor(tm, 1));
                tm = fmaxf(tm, __shfl_xor(tm, 2));
                tm = fmaxf(tm, __shfl_xor(tm, 4));
                tm = fmaxf(tm, __shfl_xor(tm, 8));
                const float mnew = fmaxf(mrun[rg], tm);
                const float corr = exp2f(mrun[rg] - mnew);
                pacc[0][rg] *= corr;
                pacc[1][rg] *= corr;
                float s6[6];
#pragma unroll
                for (int i = 0; i < 6; ++i) {
                    float e0 = exp2f(sacc[2 * i][rg] - mnew);
                    float e1 = exp2f(sacc[2 * i + 1][rg] - mnew);
                    sacc[2 * i][rg] = e0; sacc[2 * i + 1][rg] = e1;
                    s6[i] = e0 + e1;
                }
                srun[rg] = srun[rg] * corr +
                           (((s6[0] + s6[1]) + (s6[2] + s6[3])) + (s6[4] + s6[5]));
                mrun[rg] = mnew;
            }
            // pack P + PV, 2 chunks of 96 tokens
#pragma unroll
            for (int c2 = 0; c2 < 2; ++c2) {
#pragma unroll
                for (int kc = 0; kc < 6; ++kc) {
#pragma unroll
                    for (int rg = 0; rg < 4; ++rg) {
                        int q = lg * 4 + rg;
                        myP[q * 104 + kc * 16 + lr] = f2bf(sacc[c2 * 6 + kc][rg]);
                    }
                }
#pragma unroll
                for (int k2 = 0; k2 < 3; ++k2) {
                    b16x8 pf = *(const b16x8*)(myP + lr * 104 + k2 * 32 + lg * 8);
#pragma unroll
                    for (int nt = 0; nt < 2; ++nt) {
                        b16x8 vf = *(const b16x8*)(vt + base +
                                                   (size_t)(nt * 16 + lr) * 384 +
                                                   half * 192 + c2 * 96 + k2 * 32 + lg * 8);
                        pacc[nt] = __builtin_amdgcn_mfma_f32_16x16x32_bf16(pf, vf, pacc[nt], 0, 0, 0);
                    }
                }
            }
        }
        // epilogue: normalize, store head-major A [l][h][t][32]
        float rs[4];
#pragma unroll
        for (int rg = 0; rg < 4; ++rg) {
            float ss = srun[rg];
            ss += __shfl_xor(ss, 1); ss += __shfl_xor(ss, 2);
            ss += __shfl_xor(ss, 4); ss += __shfl_xor(ss, 8);
            rs[rg] = __builtin_amdgcn_rcpf(ss);
        }
#pragma unroll
        for (int nt = 0; nt < 2; ++nt) {
#pragma unroll
            for (int rg = 0; rg < 4; ++rg) {
                size_t trow = (size_t)(qt * 16 + lg * 4 + rg);
                ah[base + trow * 32 + nt * 16 + lr] = f2bf(pacc[nt][rg] * rs[rg]);
            }
        }
    }
}

// ---------------------------------------------------------------------------
// K3: z = a @ Wp + bp with mean over n folded into the accumulator.
//     grid (256 l, 4 col-quarters), 256 thr (wm 0..3). A is head-major.
// ---------------------------------------------------------------------------
__global__ __launch_bounds__(256, 4) void k_proj_mean(const u16* __restrict__ ah,
                                                      const u16* __restrict__ wtp,
                                                      const float* __restrict__ bp,
                                                      float* __restrict__ out) {
    __shared__ u16 sW[4096];   // 32 n-rows x 128 k (8 KB), swizzle preserved
    const int tid = threadIdx.x;
    const int l = blockIdx.x, cq = blockIdx.y;
#pragma unroll
    for (int it = 0; it < 2; ++it) {
        int e = (it * 256 + tid) << 3;
        *(b16x8*)(sW + e) = *(const b16x8*)(wtp + cq * 4096 + e);
    }
    __syncthreads();
    const int wm = tid >> 6, lane = tid & 63, lr = lane & 15, lg = lane >> 4;
    f32x4 acc[2];
    acc[0] = (f32x4){0.f, 0.f, 0.f, 0.f};
    acc[1] = (f32x4){0.f, 0.f, 0.f, 0.f};
#pragma unroll
    for (int nn = 0; nn < 6; ++nn) {
        const int t = nn * 64 + wm * 16 + lr;      // w-rows fixed per wm -> mean folds
#pragma unroll
        for (int kt = 0; kt < 4; ++kt) {           // kt = head (A is [l][h][t][32])
            b16x8 af = *(const b16x8*)(ah + ((size_t)(l * 4 + kt) * 384 + t) * 32 + lg * 8);
            const int ch = kt * 4 + lg;
#pragma unroll
            for (int nt = 0; nt < 2; ++nt) {
                const int ncl = nt * 16 + lr;      // local n-row; (global n)&7 == ncl&7
                b16x8 bf = *(const b16x8*)(sW + ncl * 128 + ((ch ^ (ncl & 7)) << 3));
                acc[nt] = __builtin_amdgcn_mfma_f32_16x16x32_bf16(af, bf, acc[nt], 0, 0, 0);
            }
        }
    }
#pragma unroll
    for (int nt = 0; nt < 2; ++nt) {
        const int col = cq * 32 + nt * 16 + lr;
        const float bb = bp[col];
#pragma unroll
        for (int rg = 0; rg < 4; ++rg) {
            const int wrow = wm * 16 + lg * 4 + rg;
            out[((size_t)l * 64 + wrow) * 128 + col] = acc[nt][rg] * (1.0f / 6.0f) + bb;
        }
    }
}

// ---------------------------------------------------------------------------
extern "C" void kernel_launch(void* const* d_in, const int* in_sizes, int n_in,
                              void* d_out, int out_size, void* d_ws, size_t ws_size,
                              hipStream_t stream) {
    (void)in_sizes; (void)n_in; (void)out_size; (void)ws_size;
    const float* q      = (const float*)d_in[0];
    const float* k      = (const float*)d_in[1];
    const float* v      = (const float*)d_in[2];
    const float* ln_q_g = (const float*)d_in[3];
    const float* ln_q_b = (const float*)d_in[4];
    const float* ln_k_g = (const float*)d_in[5];
    const float* ln_k_b = (const float*)d_in[6];
    const float* ln_v_g = (const float*)d_in[7];
    const float* ln_v_b = (const float*)d_in[8];
    const float* Wq     = (const float*)d_in[9];
    const float* bq     = (const float*)d_in[10];
    const float* Wk     = (const float*)d_in[11];
    const float* bk     = (const float*)d_in[12];
    const float* Wv     = (const float*)d_in[13];
    const float* bv     = (const float*)d_in[14];
    const float* Wp     = (const float*)d_in[15];
    const float* bp     = (const float*)d_in[16];
    float* out = (float*)d_out;

    u16* ws = (u16*)d_ws;
    const long long MATE = 98304LL * 128;
    u16* wQ  = ws;                          // [l][h][t][32]
    u16* wK  = ws + MATE;                   // [l][h][t][32]
    u16* wVt = ws + 2 * MATE;               // [l][h][dh][t]
    u16* wA  = ws + 3 * MATE;               // [l][h][t][32]
    u16* wWt = ws + 4 * MATE;               // 4 x 16384 packed swizzled weights

    k_pack_w<<<16, 256, 0, stream>>>(Wq, Wk, Wv, Wp, wWt);

    K1Args args;
    args.x[0] = q;       args.x[1] = k;       args.x[2] = v;
    args.lng[0] = ln_q_g; args.lng[1] = ln_k_g; args.lng[2] = ln_v_g;
    args.lnb[0] = ln_q_b; args.lnb[1] = ln_k_b; args.lnb[2] = ln_v_b;
    args.bias[0] = bq;   args.bias[1] = bk;   args.bias[2] = bv;
    args.outQ = wQ;      args.outK = wK;      args.outVt = wVt;
    k_ln_proj<<<dim3(768, 3), 512, 0, stream>>>(args, wWt);

    k_attn<<<dim3(256, 4), 256, 0, stream>>>(wQ, wK, wVt, wA);

    k_proj_mean<<<dim3(256, 4), 256, 0, stream>>>(wA, wWt + 3 * 16384, bp, out);
}